// Round 7
// baseline (921.028 us; speedup 1.0000x reference)
//
#include <hip/hip_runtime.h>
#include <math.h>

#define IN_C 64
#define HC 128      // H*OUT_C
#define NHEAD 4
#define EWD 16
#define NEG 0.2f

__device__ __forceinline__ float lrelu(float v) { return v > 0.f ? v : NEG * v; }
// f32 -> bf16 (RNE)
__device__ __forceinline__ unsigned short f2b(float f) {
    unsigned int u = __float_as_uint(f);
    unsigned int r = ((u >> 16) & 1u) + 0x7fffu;
    return (unsigned short)((u + r) >> 16);
}
// bf16 bits -> f32
__device__ __forceinline__ float b2f(unsigned int lo16) {
    return __uint_as_float(lo16 << 16);
}
// extract this thread's head's ex from packed record
__device__ __forceinline__ float pickex(uint4 rec, int head) {
    unsigned int pair = (head & 2) ? rec.z : rec.y;
    unsigned int bits = (head & 1) ? (pair >> 16) : (pair & 0xffffu);
    return b2f(bits);
}

// ---------------------------------------------------------------- K1: h(bf16) = x@W, a_src, a_dst
// Register-tiled GEMM: 256 thr, 64x128 block tile, 8x4 thread tile.
// acc[8][4]+a4[8] ~95 VGPR, all static indices -> no spill (bounds cap 170).
__global__ void __launch_bounds__(256, 3)
k_feat(const float* __restrict__ x, const float* __restrict__ W,
       const float* __restrict__ att_s, const float* __restrict__ att_d,
       unsigned short* __restrict__ h_bf, float* __restrict__ a_src,
       float* __restrict__ a_dst, int N) {
    __shared__ float sA[64 * IN_C];          // 16 KB, [row][k]
    __shared__ float sB[IN_C * HC];          // 32 KB, [k][c]
    const int tid = threadIdx.x;
    const int tr = tid >> 5;                 // 0..7: row-group
    const int tc = tid & 31;                 // 0..31: col within head
    {
        const float4* W4 = (const float4*)W;
        float4* B4 = (float4*)sB;
#pragma unroll
        for (int i = 0; i < 8; ++i) B4[tid + i * 256] = W4[tid + i * 256];
    }
    float as[4], ad[4];
#pragma unroll
    for (int j = 0; j < 4; ++j) { as[j] = att_s[tc + 32 * j]; ad[j] = att_d[tc + 32 * j]; }

    for (int base = blockIdx.x * 64; base < N; base += gridDim.x * 64) {
        const int nrows = min(64, N - base);
        __syncthreads();                     // protect sA reuse (and sB on 1st iter)
        const float4* x4 = (const float4*)(x + (size_t)base * IN_C);
#pragma unroll
        for (int i = 0; i < 4; ++i) {        // 64x64 floats = 1024 float4 / 256 thr
            int g = tid + i * 256;
            if ((g >> 4) < nrows) ((float4*)sA)[g] = x4[g];
        }
        __syncthreads();
        float acc[8][4];
#pragma unroll
        for (int i = 0; i < 8; ++i)
#pragma unroll
            for (int j = 0; j < 4; ++j) acc[i][j] = 0.f;
#pragma unroll
        for (int k4 = 0; k4 < IN_C / 4; ++k4) {
            float4 a4[8];
#pragma unroll
            for (int i = 0; i < 8; ++i)      // b128, 2 addrs/wave -> free
                a4[i] = *(const float4*)&sA[(tr + 8 * i) * IN_C + 4 * k4];
#pragma unroll
            for (int kk = 0; kk < 4; ++kk) {
                float b[4];
#pragma unroll
                for (int j = 0; j < 4; ++j)  // 32 distinct banks, broadcast over tr
                    b[j] = sB[(4 * k4 + kk) * HC + tc + 32 * j];
#pragma unroll
                for (int i = 0; i < 8; ++i) {
                    const float av = (kk == 0) ? a4[i].x : (kk == 1) ? a4[i].y
                                   : (kk == 2) ? a4[i].z : a4[i].w;
#pragma unroll
                    for (int j = 0; j < 4; ++j)
                        acc[i][j] = fmaf(av, b[j], acc[i][j]);
                }
            }
        }
#pragma unroll
        for (int i = 0; i < 8; ++i) {
            const int r = tr + 8 * i;
            const int n = base + r;
            if (r < nrows) {
#pragma unroll
                for (int j = 0; j < 4; ++j)
                    h_bf[(size_t)n * HC + tc + 32 * j] = f2b(acc[i][j]);
#pragma unroll
                for (int j = 0; j < 4; ++j) {    // head == j for this thread's col j
                    float ps = acc[i][j] * as[j];
                    float pd = acc[i][j] * ad[j];
#pragma unroll
                    for (int off = 16; off; off >>= 1) {
                        ps += __shfl_xor(ps, off, 32);
                        pd += __shfl_xor(pd, off, 32);
                    }
                    if (tc == 0) {
                        a_src[n * NHEAD + j] = ps;
                        a_dst[n * NHEAD + j] = pd;
                    }
                }
            }
        }
    }
}

// ---------------------------------------------------------------- degree histogram (4 edges/thread)
__global__ void k_count(const int* __restrict__ dst, int* __restrict__ deg, int E) {
    const int ebase = blockIdx.x * 1024 + threadIdx.x;
    int d[4];
#pragma unroll
    for (int i = 0; i < 4; ++i) {
        int e = ebase + i * 256;
        d[i] = (e < E) ? dst[e] : -1;
    }
#pragma unroll
    for (int i = 0; i < 4; ++i)
        if (d[i] >= 0) atomicAdd(&deg[d[i]], 1);
}

// ---------------------------------------------------------------- 3-kernel exclusive scan (chunks of 1024)
__global__ void k_scan1(const int* __restrict__ deg, int* __restrict__ part, int N) {
    const int b = blockIdx.x, tid = threadIdx.x;  // 256
    int base = b * 1024 + tid * 4;
    int s = 0;
#pragma unroll
    for (int k = 0; k < 4; ++k) { int i = base + k; if (i < N) s += deg[i]; }
#pragma unroll
    for (int off = 32; off; off >>= 1) s += __shfl_xor(s, off, 64);
    __shared__ int ls[4];
    if ((tid & 63) == 0) ls[tid >> 6] = s;
    __syncthreads();
    if (tid == 0) part[b] = ls[0] + ls[1] + ls[2] + ls[3];
}

__global__ void k_scan2(int* part, int nb) {
    const int tid = threadIdx.x;  // 64, nb <= 64
    int orig = (tid < nb) ? part[tid] : 0;
    int v = orig;
#pragma unroll
    for (int off = 1; off < 64; off <<= 1) {
        int t = __shfl_up(v, off, 64);
        if (tid >= off) v += t;
    }
    if (tid < nb) part[tid] = v - orig;  // exclusive
}

__global__ void k_scan3(const int* __restrict__ deg, const int* __restrict__ part,
                        int* __restrict__ rowptr, int* __restrict__ cursor, int N, int E) {
    const int b = blockIdx.x, tid = threadIdx.x;  // 256
    int base = b * 1024 + tid * 4;
    int d[4]; int s = 0;
#pragma unroll
    for (int k = 0; k < 4; ++k) { int i = base + k; d[k] = (i < N) ? deg[i] : 0; s += d[k]; }
    int v = s;
#pragma unroll
    for (int off = 1; off < 64; off <<= 1) {
        int t = __shfl_up(v, off, 64);
        if ((tid & 63) >= off) v += t;
    }
    __shared__ int wsum[4];
    if ((tid & 63) == 63) wsum[tid >> 6] = v;
    __syncthreads();
    int waveoff = 0;
    const int w = tid >> 6;
    for (int k = 0; k < w; ++k) waveoff += wsum[k];
    int excl = v - s + waveoff + part[b];
#pragma unroll
    for (int k = 0; k < 4; ++k) {
        int i = base + k;
        if (i < N) { rowptr[i] = excl; cursor[i] = excl; }
        excl += d[k];
    }
    if (b == 0 && tid == 0) rowptr[N] = E;
}

// ---------------------------------------------------------------- fused fill: 4 edges/thread for MLP
__global__ void k_fill(const int* __restrict__ src, const int* __restrict__ dst,
                       const float* __restrict__ ew, const float* __restrict__ Wl,
                       const float* __restrict__ bl,
                       const float* __restrict__ a_src, const float* __restrict__ a_dst,
                       int* __restrict__ cursor, uint4* __restrict__ csr,
                       float* __restrict__ partial, int E) {
    __shared__ float sW[EWD * NHEAD];
    __shared__ float sb[NHEAD];
    __shared__ float sred[4][4];
    const int tid = threadIdx.x;  // 256; edges tid, tid+256, tid+512, tid+768
    if (tid < EWD * NHEAD) sW[tid] = Wl[tid];
    if (tid < NHEAD) sb[tid] = bl[tid];
    __syncthreads();
    const int ebase = blockIdx.x * 1024 + tid;
    bool val[4]; int sn[4], dn[4];
#pragma unroll
    for (int i = 0; i < 4; ++i) {
        int e = ebase + i * 256;
        val[i] = e < E;
        int ec = val[i] ? e : 0;
        sn[i] = src[ec];
        dn[i] = dst[ec];
    }
    float4 as4[4], ad4[4];
#pragma unroll
    for (int i = 0; i < 4; ++i) {     // 8 independent gathers in flight
        as4[i] = ((const float4*)a_src)[sn[i]];
        ad4[i] = ((const float4*)a_dst)[dn[i]];
    }
    float loc[4] = {0.f, 0.f, 0.f, 0.f};
    unsigned int recy[4], recz[4];
#pragma unroll
    for (int i = 0; i < 4; ++i) {
        int ec = val[i] ? (ebase + i * 256) : 0;
        const float4* w4 = (const float4*)(ew + (size_t)ec * EWD);
        float v[4];
#pragma unroll
        for (int hh = 0; hh < 4; ++hh) v[hh] = sb[hh];
#pragma unroll
        for (int q = 0; q < 4; ++q) {
            float4 t = w4[q];
            float tv[4] = {t.x, t.y, t.z, t.w};
#pragma unroll
            for (int k = 0; k < 4; ++k)
#pragma unroll
                for (int hh = 0; hh < 4; ++hh)
                    v[hh] = fmaf(tv[k], sW[(q * 4 + k) * 4 + hh], v[hh]);
        }
        float m = fmaxf(fmaxf(v[0], v[1]), fmaxf(v[2], v[3]));
        float s = 0.f;
#pragma unroll
        for (int hh = 0; hh < 4; ++hh) { v[hh] = __expf(v[hh] - m); s += v[hh]; }
        float inv = 1.f / s;
#pragma unroll
        for (int hh = 0; hh < 4; ++hh) {
            v[hh] *= inv;
            if (val[i]) loc[hh] += v[hh];
        }
        unsigned int e0 = f2b(__expf(lrelu(as4[i].x + ad4[i].x + v[0])));
        unsigned int e1 = f2b(__expf(lrelu(as4[i].y + ad4[i].y + v[1])));
        unsigned int e2 = f2b(__expf(lrelu(as4[i].z + ad4[i].z + v[2])));
        unsigned int e3 = f2b(__expf(lrelu(as4[i].w + ad4[i].w + v[3])));
        recy[i] = e0 | (e1 << 16);
        recz[i] = e2 | (e3 << 16);
    }
    int slot[4];
#pragma unroll
    for (int i = 0; i < 4; ++i)       // 4 independent atomics in flight
        slot[i] = val[i] ? atomicAdd(&cursor[dn[i]], 1) : 0;
#pragma unroll
    for (int i = 0; i < 4; ++i) {
        if (val[i]) {
            uint4 rec;
            rec.x = (unsigned int)sn[i];
            rec.y = recy[i];
            rec.z = recz[i];
            rec.w = 0u;
            csr[slot[i]] = rec;       // single scattered 16B
        }
    }
    // block-level partial sums of edge_alpha (for self-loop mean)
    const int w = tid >> 6;
#pragma unroll
    for (int hh = 0; hh < 4; ++hh) {
        float v = loc[hh];
#pragma unroll
        for (int off = 32; off; off >>= 1) v += __shfl_xor(v, off, 64);
        if ((tid & 63) == 0) sred[w][hh] = v;
    }
    __syncthreads();
    if (tid < 4)
        partial[blockIdx.x * 4 + tid] =
            sred[0][tid] + sred[1][tid] + sred[2][tid] + sred[3][tid];
}

// ---------------------------------------------------------------- reduce partials -> asum[4]
__global__ void k_red(const float* __restrict__ partial, float* __restrict__ asum, int nb) {
    const int tid = threadIdx.x;  // 256: wave w handles head w
    const int w = tid >> 6, lane = tid & 63;
    float s = 0.f;
    for (int b = lane; b < nb; b += 64) s += partial[b * 4 + w];
#pragma unroll
    for (int off = 32; off; off >>= 1) s += __shfl_xor(s, off, 64);
    if (lane == 0) asum[w] = s;
}

// ---------------------------------------------------------------- aggregate: one block (128 thr) per dst node, no LDS
__global__ void k_agg(const unsigned short* __restrict__ h_bf, const int* __restrict__ rowptr,
                      const uint4* __restrict__ csr,
                      const float* __restrict__ a_src, const float* __restrict__ a_dst,
                      const float* __restrict__ asum, const float* __restrict__ bias,
                      float* __restrict__ out, int N, int E) {
    const int d = blockIdx.x;
    const int tid = threadIdx.x;   // 128: one output channel each
    const int head = tid >> 5;
    const int r0 = rowptr[d], r1 = rowptr[d + 1];
    float acc = 0.f, den = 0.f;
    int k = r0;
    for (; k + 4 <= r1; k += 4) {               // 4 independent h-gathers in flight
        const uint4 rA = csr[k], rB = csr[k + 1], rC = csr[k + 2], rD = csr[k + 3];
        const float hA = b2f(h_bf[(size_t)rA.x * HC + tid]);
        const float hB = b2f(h_bf[(size_t)rB.x * HC + tid]);
        const float hC = b2f(h_bf[(size_t)rC.x * HC + tid]);
        const float hD = b2f(h_bf[(size_t)rD.x * HC + tid]);
        const float eA = pickex(rA, head), eB = pickex(rB, head);
        const float eC = pickex(rC, head), eD = pickex(rD, head);
        acc = fmaf(hA, eA, acc); den += eA;
        acc = fmaf(hB, eB, acc); den += eB;
        acc = fmaf(hC, eC, acc); den += eC;
        acc = fmaf(hD, eD, acc); den += eD;
    }
    for (; k < r1; ++k) {
        const uint4 rec = csr[k];
        const float hv = b2f(h_bf[(size_t)rec.x * HC + tid]);
        const float ev = pickex(rec, head);
        acc = fmaf(hv, ev, acc); den += ev;
    }
    // self loop: ea = mean(edge_alpha), src = dst = d
    const float mean = asum[head] * (1.0f / (float)E);
    float l = lrelu(a_src[d * NHEAD + head] + a_dst[d * NHEAD + head] + mean);
    const float exl = __expf(l);
    acc = fmaf(b2f(h_bf[(size_t)d * HC + tid]), exl, acc);
    den += exl;
    out[(size_t)d * HC + tid] = acc / (den + 1e-16f) + bias[tid];
}

// ----------------------------------------------------------------
extern "C" void kernel_launch(void* const* d_in, const int* in_sizes, int n_in,
                              void* d_out, int out_size, void* d_ws, size_t ws_size,
                              hipStream_t stream) {
    const float* x     = (const float*)d_in[0];
    const int*   ei    = (const int*)d_in[1];
    const float* ew    = (const float*)d_in[2];
    const float* W     = (const float*)d_in[3];
    const float* bias  = (const float*)d_in[4];
    const float* att_s = (const float*)d_in[5];
    const float* att_d = (const float*)d_in[6];
    const float* Wl    = (const float*)d_in[7];
    const float* bl    = (const float*)d_in[8];
    const int N = in_sizes[0] / IN_C;
    const int E = in_sizes[1] / 2;
    const int* src = ei;
    const int* dst = ei + E;
    float* out = (float*)d_out;

    const int FILL_BLOCKS = (E + 1023) / 1024;   // 782: 4 edges per thread
    const int FEAT_BLOCKS = (N + 63) / 64;       // 782: 64 rows per block

    float* ws = (float*)d_ws;
    size_t off = 0;
    unsigned short* h_bf = (unsigned short*)(ws + off); off += (size_t)N * HC / 2;  // 12.8 MB
    float* a_src  = ws + off; off += (size_t)N * NHEAD;
    float* a_dst  = ws + off; off += (size_t)N * NHEAD;
    int*   deg    = (int*)(ws + off); off += N;          // zeroed
    float* asum   = ws + off; off += 4;
    int*   part   = (int*)(ws + off); off += 64;
    int*   rowptr = (int*)(ws + off); off += (size_t)N + 4;
    int*   cursor = (int*)(ws + off); off += N;
    uint4* csr    = (uint4*)(ws + off); off += (size_t)E * 4;      // 12.8 MB
    float* partial= ws + off; off += (size_t)FILL_BLOCKS * 4;      // ~27 MB total

    hipMemsetAsync(deg, 0, (size_t)N * 4, stream);

    k_feat<<<FEAT_BLOCKS, 256, 0, stream>>>(x, W, att_s, att_d, h_bf, a_src, a_dst, N);
    k_count<<<FILL_BLOCKS, 256, 0, stream>>>(dst, deg, E);
    const int nb = (N + 1023) / 1024;  // 49 <= 64
    k_scan1<<<nb, 256, 0, stream>>>(deg, part, N);
    k_scan2<<<1, 64, 0, stream>>>(part, nb);
    k_scan3<<<nb, 256, 0, stream>>>(deg, part, rowptr, cursor, N, E);
    k_fill<<<FILL_BLOCKS, 256, 0, stream>>>(src, dst, ew, Wl, bl, a_src, a_dst,
                                            cursor, csr, partial, E);
    k_red<<<1, 256, 0, stream>>>(partial, asum, FILL_BLOCKS);
    k_agg<<<N, 128, 0, stream>>>(h_bf, rowptr, csr, a_src, a_dst,
                                 asum, bias, out, N, E);
}

// Round 8
// 360.690 us; speedup vs baseline: 2.5535x; 2.5535x over previous
//
#include <hip/hip_runtime.h>
#include <math.h>

#define IN_C 64
#define HC 128      // H*OUT_C
#define NHEAD 4
#define EWD 16
#define NEG 0.2f

__device__ __forceinline__ float lrelu(float v) { return v > 0.f ? v : NEG * v; }
// f32 -> bf16 (RNE)
__device__ __forceinline__ unsigned short f2b(float f) {
    unsigned int u = __float_as_uint(f);
    unsigned int r = ((u >> 16) & 1u) + 0x7fffu;
    return (unsigned short)((u + r) >> 16);
}
// bf16 bits -> f32
__device__ __forceinline__ float b2f(unsigned int lo16) {
    return __uint_as_float(lo16 << 16);
}
// extract this thread's head's ex from packed record
__device__ __forceinline__ float pickex(uint4 rec, int head) {
    unsigned int pair = (head & 2) ? rec.z : rec.y;
    unsigned int bits = (head & 1) ? (pair >> 16) : (pair & 0xffffu);
    return b2f(bits);
}

// ---------------------------------------------------------------- K1: h(bf16) = x@W, a_src, a_dst
// PROVEN-SAFE structure (R1-R4: no scratch, <59us): 128 thr = channels,
// W in 32KB LDS, xs broadcast. c-outer loop reuses each Ws read over 4 rows.
// acc[4]+wv ~20 VGPR, all static indices after unroll.
__global__ void __launch_bounds__(128)
k_feat(const float* __restrict__ x, const float* __restrict__ W,
       const float* __restrict__ att_s, const float* __restrict__ att_d,
       unsigned short* __restrict__ h_bf, float* __restrict__ a_src,
       float* __restrict__ a_dst, int N) {
    __shared__ float Ws[IN_C * HC];   // 32 KB
    __shared__ float xs[4][IN_C];
    const int tid = threadIdx.x;      // 128 threads = output channels
    {
        const float4* W4 = (const float4*)W;
        float4* Ws4 = (float4*)Ws;
#pragma unroll
        for (int i = 0; i < 16; ++i)
            Ws4[tid + i * 128] = W4[tid + i * 128];
    }
    const float as = att_s[tid];
    const float ad = att_d[tid];
    const int head = tid >> 5;
    for (int base = blockIdx.x * 4; base < N; base += gridDim.x * 4) {
        const int nrows = min(4, N - base);
        __syncthreads();              // protect xs reuse (and Ws on 1st iter)
        if (tid < 64) {
            int r = tid >> 4, q = tid & 15;
            if (r < nrows)
                ((float4*)&xs[r][0])[q] = ((const float4*)(x + (size_t)(base + r) * IN_C))[q];
        }
        __syncthreads();
        float acc[4] = {0.f, 0.f, 0.f, 0.f};
#pragma unroll
        for (int c = 0; c < IN_C; ++c) {
            const float wv = Ws[c * HC + tid];   // 1 LDS read reused 4x
#pragma unroll
            for (int r = 0; r < 4; ++r)
                acc[r] = fmaf(xs[r][c], wv, acc[r]);  // xs: same-addr broadcast
        }
#pragma unroll
        for (int r = 0; r < 4; ++r) {
            const int n = base + r;
            if (r < nrows) {
                h_bf[(size_t)n * HC + tid] = f2b(acc[r]);
                float ps = acc[r] * as, pd = acc[r] * ad;
#pragma unroll
                for (int off = 16; off; off >>= 1) {
                    ps += __shfl_xor(ps, off, 32);
                    pd += __shfl_xor(pd, off, 32);
                }
                if ((tid & 31) == 0) {
                    a_src[n * NHEAD + head] = ps;
                    a_dst[n * NHEAD + head] = pd;
                }
            }
        }
    }
}

// ---------------------------------------------------------------- degree histogram (4 edges/thread)
__global__ void k_count(const int* __restrict__ dst, int* __restrict__ deg, int E) {
    const int ebase = blockIdx.x * 1024 + threadIdx.x;
    int d[4];
#pragma unroll
    for (int i = 0; i < 4; ++i) {
        int e = ebase + i * 256;
        d[i] = (e < E) ? dst[e] : -1;
    }
#pragma unroll
    for (int i = 0; i < 4; ++i)
        if (d[i] >= 0) atomicAdd(&deg[d[i]], 1);
}

// ---------------------------------------------------------------- 3-kernel exclusive scan (chunks of 1024)
__global__ void k_scan1(const int* __restrict__ deg, int* __restrict__ part, int N) {
    const int b = blockIdx.x, tid = threadIdx.x;  // 256
    int base = b * 1024 + tid * 4;
    int s = 0;
#pragma unroll
    for (int k = 0; k < 4; ++k) { int i = base + k; if (i < N) s += deg[i]; }
#pragma unroll
    for (int off = 32; off; off >>= 1) s += __shfl_xor(s, off, 64);
    __shared__ int ls[4];
    if ((tid & 63) == 0) ls[tid >> 6] = s;
    __syncthreads();
    if (tid == 0) part[b] = ls[0] + ls[1] + ls[2] + ls[3];
}

__global__ void k_scan2(int* part, int nb) {
    const int tid = threadIdx.x;  // 64, nb <= 64
    int orig = (tid < nb) ? part[tid] : 0;
    int v = orig;
#pragma unroll
    for (int off = 1; off < 64; off <<= 1) {
        int t = __shfl_up(v, off, 64);
        if (tid >= off) v += t;
    }
    if (tid < nb) part[tid] = v - orig;  // exclusive
}

__global__ void k_scan3(const int* __restrict__ deg, const int* __restrict__ part,
                        int* __restrict__ rowptr, int* __restrict__ cursor, int N, int E) {
    const int b = blockIdx.x, tid = threadIdx.x;  // 256
    int base = b * 1024 + tid * 4;
    int d[4]; int s = 0;
#pragma unroll
    for (int k = 0; k < 4; ++k) { int i = base + k; d[k] = (i < N) ? deg[i] : 0; s += d[k]; }
    int v = s;
#pragma unroll
    for (int off = 1; off < 64; off <<= 1) {
        int t = __shfl_up(v, off, 64);
        if ((tid & 63) >= off) v += t;
    }
    __shared__ int wsum[4];
    if ((tid & 63) == 63) wsum[tid >> 6] = v;
    __syncthreads();
    int waveoff = 0;
    const int w = tid >> 6;
    for (int k = 0; k < w; ++k) waveoff += wsum[k];
    int excl = v - s + waveoff + part[b];
#pragma unroll
    for (int k = 0; k < 4; ++k) {
        int i = base + k;
        if (i < N) { rowptr[i] = excl; cursor[i] = excl; }
        excl += d[k];
    }
    if (b == 0 && tid == 0) rowptr[N] = E;
}

// ---------------------------------------------------------------- fused fill: 4 edges/thread for MLP
__global__ void k_fill(const int* __restrict__ src, const int* __restrict__ dst,
                       const float* __restrict__ ew, const float* __restrict__ Wl,
                       const float* __restrict__ bl,
                       const float* __restrict__ a_src, const float* __restrict__ a_dst,
                       int* __restrict__ cursor, uint4* __restrict__ csr,
                       float* __restrict__ partial, int E) {
    __shared__ float sW[EWD * NHEAD];
    __shared__ float sb[NHEAD];
    __shared__ float sred[4][4];
    const int tid = threadIdx.x;  // 256; edges tid, tid+256, tid+512, tid+768
    if (tid < EWD * NHEAD) sW[tid] = Wl[tid];
    if (tid < NHEAD) sb[tid] = bl[tid];
    __syncthreads();
    const int ebase = blockIdx.x * 1024 + tid;
    bool val[4]; int sn[4], dn[4];
#pragma unroll
    for (int i = 0; i < 4; ++i) {
        int e = ebase + i * 256;
        val[i] = e < E;
        int ec = val[i] ? e : 0;
        sn[i] = src[ec];
        dn[i] = dst[ec];
    }
    float4 as4[4], ad4[4];
#pragma unroll
    for (int i = 0; i < 4; ++i) {     // 8 independent gathers in flight
        as4[i] = ((const float4*)a_src)[sn[i]];
        ad4[i] = ((const float4*)a_dst)[dn[i]];
    }
    float loc[4] = {0.f, 0.f, 0.f, 0.f};
    unsigned int recy[4], recz[4];
#pragma unroll
    for (int i = 0; i < 4; ++i) {
        int ec = val[i] ? (ebase + i * 256) : 0;
        const float4* w4 = (const float4*)(ew + (size_t)ec * EWD);
        float v[4];
#pragma unroll
        for (int hh = 0; hh < 4; ++hh) v[hh] = sb[hh];
#pragma unroll
        for (int q = 0; q < 4; ++q) {
            float4 t = w4[q];
            float tv[4] = {t.x, t.y, t.z, t.w};
#pragma unroll
            for (int k = 0; k < 4; ++k)
#pragma unroll
                for (int hh = 0; hh < 4; ++hh)
                    v[hh] = fmaf(tv[k], sW[(q * 4 + k) * 4 + hh], v[hh]);
        }
        float m = fmaxf(fmaxf(v[0], v[1]), fmaxf(v[2], v[3]));
        float s = 0.f;
#pragma unroll
        for (int hh = 0; hh < 4; ++hh) { v[hh] = __expf(v[hh] - m); s += v[hh]; }
        float inv = 1.f / s;
#pragma unroll
        for (int hh = 0; hh < 4; ++hh) {
            v[hh] *= inv;
            if (val[i]) loc[hh] += v[hh];
        }
        unsigned int e0 = f2b(__expf(lrelu(as4[i].x + ad4[i].x + v[0])));
        unsigned int e1 = f2b(__expf(lrelu(as4[i].y + ad4[i].y + v[1])));
        unsigned int e2 = f2b(__expf(lrelu(as4[i].z + ad4[i].z + v[2])));
        unsigned int e3 = f2b(__expf(lrelu(as4[i].w + ad4[i].w + v[3])));
        recy[i] = e0 | (e1 << 16);
        recz[i] = e2 | (e3 << 16);
    }
    int slot[4];
#pragma unroll
    for (int i = 0; i < 4; ++i)       // 4 independent atomics in flight
        slot[i] = val[i] ? atomicAdd(&cursor[dn[i]], 1) : 0;
#pragma unroll
    for (int i = 0; i < 4; ++i) {
        if (val[i]) {
            uint4 rec;
            rec.x = (unsigned int)sn[i];
            rec.y = recy[i];
            rec.z = recz[i];
            rec.w = 0u;
            csr[slot[i]] = rec;       // single scattered 16B
        }
    }
    // block-level partial sums of edge_alpha (for self-loop mean)
    const int w = tid >> 6;
#pragma unroll
    for (int hh = 0; hh < 4; ++hh) {
        float v = loc[hh];
#pragma unroll
        for (int off = 32; off; off >>= 1) v += __shfl_xor(v, off, 64);
        if ((tid & 63) == 0) sred[w][hh] = v;
    }
    __syncthreads();
    if (tid < 4)
        partial[blockIdx.x * 4 + tid] =
            sred[0][tid] + sred[1][tid] + sred[2][tid] + sred[3][tid];
}

// ---------------------------------------------------------------- reduce partials -> asum[4]
__global__ void k_red(const float* __restrict__ partial, float* __restrict__ asum, int nb) {
    const int tid = threadIdx.x;  // 256: wave w handles head w
    const int w = tid >> 6, lane = tid & 63;
    float s = 0.f;
    for (int b = lane; b < nb; b += 64) s += partial[b * 4 + w];
#pragma unroll
    for (int off = 32; off; off >>= 1) s += __shfl_xor(s, off, 64);
    if (lane == 0) asum[w] = s;
}

// ---------------------------------------------------------------- aggregate: one block (128 thr) per dst node, no LDS
__global__ void k_agg(const unsigned short* __restrict__ h_bf, const int* __restrict__ rowptr,
                      const uint4* __restrict__ csr,
                      const float* __restrict__ a_src, const float* __restrict__ a_dst,
                      const float* __restrict__ asum, const float* __restrict__ bias,
                      float* __restrict__ out, int N, int E) {
    const int d = blockIdx.x;
    const int tid = threadIdx.x;   // 128: one output channel each
    const int head = tid >> 5;
    const int r0 = rowptr[d], r1 = rowptr[d + 1];
    float acc = 0.f, den = 0.f;
    int k = r0;
    for (; k + 4 <= r1; k += 4) {               // 4 independent h-gathers in flight
        const uint4 rA = csr[k], rB = csr[k + 1], rC = csr[k + 2], rD = csr[k + 3];
        const float hA = b2f(h_bf[(size_t)rA.x * HC + tid]);
        const float hB = b2f(h_bf[(size_t)rB.x * HC + tid]);
        const float hC = b2f(h_bf[(size_t)rC.x * HC + tid]);
        const float hD = b2f(h_bf[(size_t)rD.x * HC + tid]);
        const float eA = pickex(rA, head), eB = pickex(rB, head);
        const float eC = pickex(rC, head), eD = pickex(rD, head);
        acc = fmaf(hA, eA, acc); den += eA;
        acc = fmaf(hB, eB, acc); den += eB;
        acc = fmaf(hC, eC, acc); den += eC;
        acc = fmaf(hD, eD, acc); den += eD;
    }
    for (; k < r1; ++k) {
        const uint4 rec = csr[k];
        const float hv = b2f(h_bf[(size_t)rec.x * HC + tid]);
        const float ev = pickex(rec, head);
        acc = fmaf(hv, ev, acc); den += ev;
    }
    // self loop: ea = mean(edge_alpha), src = dst = d
    const float mean = asum[head] * (1.0f / (float)E);
    float l = lrelu(a_src[d * NHEAD + head] + a_dst[d * NHEAD + head] + mean);
    const float exl = __expf(l);
    acc = fmaf(b2f(h_bf[(size_t)d * HC + tid]), exl, acc);
    den += exl;
    out[(size_t)d * HC + tid] = acc / (den + 1e-16f) + bias[tid];
}

// ----------------------------------------------------------------
extern "C" void kernel_launch(void* const* d_in, const int* in_sizes, int n_in,
                              void* d_out, int out_size, void* d_ws, size_t ws_size,
                              hipStream_t stream) {
    const float* x     = (const float*)d_in[0];
    const int*   ei    = (const int*)d_in[1];
    const float* ew    = (const float*)d_in[2];
    const float* W     = (const float*)d_in[3];
    const float* bias  = (const float*)d_in[4];
    const float* att_s = (const float*)d_in[5];
    const float* att_d = (const float*)d_in[6];
    const float* Wl    = (const float*)d_in[7];
    const float* bl    = (const float*)d_in[8];
    const int N = in_sizes[0] / IN_C;
    const int E = in_sizes[1] / 2;
    const int* src = ei;
    const int* dst = ei + E;
    float* out = (float*)d_out;

    const int FILL_BLOCKS = (E + 1023) / 1024;   // 782: 4 edges per thread

    float* ws = (float*)d_ws;
    size_t off = 0;
    unsigned short* h_bf = (unsigned short*)(ws + off); off += (size_t)N * HC / 2;  // 12.8 MB
    float* a_src  = ws + off; off += (size_t)N * NHEAD;
    float* a_dst  = ws + off; off += (size_t)N * NHEAD;
    int*   deg    = (int*)(ws + off); off += N;          // zeroed
    float* asum   = ws + off; off += 4;
    int*   part   = (int*)(ws + off); off += 64;
    int*   rowptr = (int*)(ws + off); off += (size_t)N + 4;
    int*   cursor = (int*)(ws + off); off += N;
    uint4* csr    = (uint4*)(ws + off); off += (size_t)E * 4;      // 12.8 MB
    float* partial= ws + off; off += (size_t)FILL_BLOCKS * 4;      // ~27 MB total

    hipMemsetAsync(deg, 0, (size_t)N * 4, stream);

    k_feat<<<2048, 128, 0, stream>>>(x, W, att_s, att_d, h_bf, a_src, a_dst, N);
    k_count<<<FILL_BLOCKS, 256, 0, stream>>>(dst, deg, E);
    const int nb = (N + 1023) / 1024;  // 49 <= 64
    k_scan1<<<nb, 256, 0, stream>>>(deg, part, N);
    k_scan2<<<1, 64, 0, stream>>>(part, nb);
    k_scan3<<<nb, 256, 0, stream>>>(deg, part, rowptr, cursor, N, E);
    k_fill<<<FILL_BLOCKS, 256, 0, stream>>>(src, dst, ew, Wl, bl, a_src, a_dst,
                                            cursor, csr, partial, E);
    k_red<<<1, 256, 0, stream>>>(partial, asum, FILL_BLOCKS);
    k_agg<<<N, 128, 0, stream>>>(h_bf, rowptr, csr, a_src, a_dst,
                                 asum, bias, out, N, E);
}